// Round 9
// baseline (2813.742 us; speedup 1.0000x reference)
//
#include <hip/hip_runtime.h>
#include <hip/hip_fp16.h>
#include <math.h>

#define NN 100000       // nodes
#define NADJ 11         // relations
#define EE 1600000      // edges per relation
#define DI 128          // input dim
#define DO 16           // output dim

#define NBINS 391       // ceil(NN / 256): 256-row coarse bins
#define BCAP 8          // LDS staging per bin
#define SEGCAP 4608     // capacity per (rel,bin): mean 4096 + 8 sigma

static constexpr float MIN_NORM = 1e-15f;
static constexpr float MAXNORM  = 1.0f - 4e-3f;   // (1-PROJ_EPS)/sqrt(c), c=1

// clang vector types: __builtin_nontemporal_* rejects HIP_vector_type
typedef float nf2 __attribute__((ext_vector_type(2)));
typedef float nf4 __attribute__((ext_vector_type(4)));

// ---------------------------------------------------------------------------
// Stage 1: per-node tangent scale  s[n] = atanh(clip(||x_n||)) / max(||x_n||,1e-15)
__global__ void k_scale(const float* __restrict__ x, float* __restrict__ scale) {
    int lane   = threadIdx.x & 63;
    int wid    = (blockIdx.x * blockDim.x + threadIdx.x) >> 6;
    int nwav   = (gridDim.x * blockDim.x) >> 6;
    for (int n = wid; n < NN; n += nwav) {
        float2 v = ((const float2*)(x + (size_t)n * DI))[lane];
        float ss = v.x * v.x + v.y * v.y;
        #pragma unroll
        for (int off = 1; off < 64; off <<= 1) ss += __shfl_xor(ss, off);
        if (lane == 0) {
            float xn = fmaxf(sqrtf(ss), MIN_NORM);
            float xc = fminf(xn, 1.0f - 1e-7f);
            scale[n] = atanhf(xc) / xn;
        }
    }
}

// ---------------------------------------------------------------------------
// Stage 2: support[j][n][o] = scale[n] * (x[n,:] @ W[j][:,o])  -> fp16.
// Split launches (G=6,G=5): acc 24/20 regs. (256,3): VGPR cap 170 (~90 used,
// no spill), 3 blocks/CU (LDS 23KB x 3 = 69KB).
template<int G>
__global__ __launch_bounds__(256, 3) void k_gemm(const float* __restrict__ x,
                                                 const float* __restrict__ scale,
                                                 const float* __restrict__ W,
                                                 __half* __restrict__ support) {
    constexpr int COLS = 16 * G;
    __shared__ float xs[64][36];
    __shared__ float ws[COLS][36];
    const int t  = threadIdx.x;
    const int tc = t & 15;
    const int tr = t >> 4;
    const int n0 = blockIdx.x * 64;

    float acc[4][G];
    #pragma unroll
    for (int m = 0; m < 4; ++m)
        #pragma unroll
        for (int j = 0; j < G; ++j) acc[m][j] = 0.f;

    for (int kb = 0; kb < 4; ++kb) {
        __syncthreads();
        for (int idx = t; idx < 64 * 8; idx += 256) {
            int r = idx >> 3, k4 = idx & 7;
            int n = n0 + r;
            float4 v = make_float4(0.f, 0.f, 0.f, 0.f);
            if (n < NN) v = ((const float4*)(x + (size_t)n * DI + kb * 32))[k4];
            *(float4*)&xs[r][k4 * 4] = v;
        }
        for (int idx = t; idx < G * 32 * 4; idx += 256) {
            int j = idx >> 7, rem = idx & 127, kk = rem >> 2, o4 = rem & 3;
            float4 v = *(const float4*)(W + ((size_t)j * DI + kb * 32 + kk) * DO + o4 * 4);
            ws[j * 16 + o4 * 4 + 0][kk] = v.x;
            ws[j * 16 + o4 * 4 + 1][kk] = v.y;
            ws[j * 16 + o4 * 4 + 2][kk] = v.z;
            ws[j * 16 + o4 * 4 + 3][kk] = v.w;
        }
        __syncthreads();
        #pragma unroll
        for (int kk4 = 0; kk4 < 8; ++kk4) {
            float4 xv[4];
            #pragma unroll
            for (int m = 0; m < 4; ++m) xv[m] = *(const float4*)&xs[tr * 4 + m][kk4 * 4];
            #pragma unroll
            for (int j = 0; j < G; ++j) {
                float4 wv = *(const float4*)&ws[j * 16 + tc][kk4 * 4];
                #pragma unroll
                for (int m = 0; m < 4; ++m)
                    acc[m][j] += xv[m].x * wv.x + xv[m].y * wv.y
                               + xv[m].z * wv.z + xv[m].w * wv.w;
            }
        }
    }
    float sv[4];
    #pragma unroll
    for (int m = 0; m < 4; ++m) {
        int n = n0 + tr * 4 + m;
        sv[m] = (n < NN) ? scale[n] : 0.f;
    }
    float* st = &xs[0][0];          // reuse as [64][17]
    const int row = t >> 2, q = t & 3;
    for (int j = 0; j < G; ++j) {
        __syncthreads();
        #pragma unroll
        for (int m = 0; m < 4; ++m)
            st[(tr * 4 + m) * 17 + tc] = acc[m][j] * sv[m];
        __syncthreads();
        int n = n0 + row;
        if (n < NN) {
            __half2 h0 = __floats2half2_rn(st[row * 17 + q * 4 + 0],
                                           st[row * 17 + q * 4 + 1]);
            __half2 h1 = __floats2half2_rn(st[row * 17 + q * 4 + 2],
                                           st[row * 17 + q * 4 + 3]);
            uint2 u;
            u.x = *(unsigned*)&h0;
            u.y = *(unsigned*)&h1;
            *(uint2*)&support[((size_t)j * NN + n) * DO + q * 4] = u;  // 8 B/lane
        }
    }
}

// ---------------------------------------------------------------------------
// Stage 3: bin edges into 256-row coarse bins (LDS staging, cooperative flush).
__global__ __launch_bounds__(256) void k_bin(const int* __restrict__ rows,
                                             const int* __restrict__ cols,
                                             const float* __restrict__ vals,
                                             int* __restrict__ gcur,
                                             float2* __restrict__ packed) {
    __shared__ int    cnt[NBINS];
    __shared__ float2 buf[NBINS][BCAP];
    __shared__ int    fl_b[256];
    __shared__ int    fl_gp[256];
    __shared__ int    nflush;

    const int t  = threadIdx.x;
    const int ro = blockIdx.y;
    const size_t ebase = (size_t)ro * EE;
    int*    cur = gcur + (size_t)ro * NBINS;
    float2* pk  = packed + (size_t)ro * NBINS * SEGCAP;

    const int nper = (EE + gridDim.x - 1) / gridDim.x;
    const int e0 = blockIdx.x * nper;
    const int e1 = (e0 + nper < EE) ? e0 + nper : EE;

    for (int b = t; b < NBINS; b += 256) cnt[b] = 0;
    __syncthreads();

    for (int eb = e0; eb < e1; eb += 256) {
        int e = eb + t;
        if (e < e1) {
            int   r = __builtin_nontemporal_load(&rows[ebase + e]);
            int   c = __builtin_nontemporal_load(&cols[ebase + e]);
            float v = __builtin_nontemporal_load(&vals[ebase + e]);
            int bin = r >> 8;
            float ptag = __uint_as_float(((unsigned)(r & 255) << 17) | (unsigned)c);
            int pos = atomicAdd(&cnt[bin], 1);
            if (pos < BCAP) {
                buf[bin][pos] = make_float2(v, ptag);
            } else {
                int gp = atomicAdd(&cur[bin], 1);
                if (gp < SEGCAP) pk[(size_t)bin * SEGCAP + gp] = make_float2(v, ptag);
            }
        }
        __syncthreads();
        if (t == 0) nflush = 0;
        __syncthreads();
        for (int b = t; b < NBINS; b += 256) {
            int c = cnt[b];
            if (c >= BCAP) {
                int i = atomicAdd(&nflush, 1);
                fl_b[i]  = b;
                fl_gp[i] = atomicAdd(&cur[b], BCAP);
                cnt[b] = 0;
            }
        }
        __syncthreads();
        int nf = nflush, o = t & 7;
        for (int j = t >> 3; j < nf; j += 32) {
            int b = fl_b[j];
            int gp = fl_gp[j] + o;
            if (gp < SEGCAP) pk[(size_t)b * SEGCAP + gp] = buf[b][o];
        }
        __syncthreads();
    }
    int o = t & 7;
    for (int b = t >> 3; b < NBINS; b += 32) {
        int c = cnt[b];
        int gp0 = 0;
        if (o == 0 && c > 0) gp0 = atomicAdd(&cur[b], c);
        gp0 = __shfl(gp0, (threadIdx.x & 63) & ~7);
        if (o < c) {
            int gp = gp0 + o;
            if (gp < SEGCAP) pk[(size_t)b * SEGCAP + gp] = buf[b][o];
        }
    }
}

// ---------------------------------------------------------------------------
// Stage 4: ONE LAUNCH PER RELATION (stream serialization => only this rel's
// 3.2 MB fp16 support slice is gathered during the launch -> L2-resident on
// every XCD). Quarter-split bins: block bx -> (bin = bx>>2, quarter = bx&3),
// 64-row LDS acc (4.4 KB). 8-edge batches, gathers only for own quarter.
__global__ __launch_bounds__(256) void k_agg(const int* __restrict__ gcur,
                                             const float2* __restrict__ packed,
                                             const __half* __restrict__ support,
                                             float* __restrict__ agg,
                                             int r0, int ro) {
    __shared__ float acc[64 * 17];
    const int bx      = blockIdx.x;
    const int bin     = bx >> 2;
    const int quarter = bx & 3;
    const int t = threadIdx.x;
    const int o = t & 15;
    const int g = t >> 4;

    for (int i = t; i < 64 * 17; i += 256) acc[i] = 0.f;
    __syncthreads();

    int c = gcur[(size_t)ro * NBINS + bin];
    if (c > SEGCAP) c = SEGCAP;
    const float2* seg = packed + ((size_t)ro * NBINS + bin) * SEGCAP;
    const __half* sup = support + (size_t)(r0 + ro) * NN * DO;

    const int nb = c >> 3;
    for (int b = g; b < nb; b += 16) {
        const float4* s4 = (const float4*)&seg[b * 8];
        float4 s0 = s4[0], s1 = s4[1], s2 = s4[2], s3 = s4[3];
        float    v[8];
        unsigned p[8];
        v[0] = s0.x; p[0] = __float_as_uint(s0.y);
        v[1] = s0.z; p[1] = __float_as_uint(s0.w);
        v[2] = s1.x; p[2] = __float_as_uint(s1.y);
        v[3] = s1.z; p[3] = __float_as_uint(s1.w);
        v[4] = s2.x; p[4] = __float_as_uint(s2.y);
        v[5] = s2.z; p[5] = __float_as_uint(s2.w);
        v[6] = s3.x; p[6] = __float_as_uint(s3.y);
        v[7] = s3.z; p[7] = __float_as_uint(s3.w);
        float sv[8];
        bool  keep[8];
        #pragma unroll
        for (int k = 0; k < 8; ++k) {
            keep[k] = (int)((p[k] >> 23) & 3u) == quarter;   // row bits 6..7
            sv[k] = keep[k] ? __half2float(sup[(size_t)(p[k] & 0x1FFFFu) * DO + o]) : 0.f;
        }
        #pragma unroll
        for (int k = 0; k < 8; ++k)
            if (keep[k])
                atomicAdd(&acc[((p[k] >> 17) & 63u) * 17 + o], v[k] * sv[k]);
    }
    if (g == 0) {
        for (int i = nb * 8; i < c; ++i) {
            float2 e = seg[i];
            unsigned p = __float_as_uint(e.y);
            if ((int)((p >> 23) & 3u) == quarter)
                atomicAdd(&acc[((p >> 17) & 63u) * 17 + o],
                          e.x * __half2float(sup[(size_t)(p & 0x1FFFFu) * DO + o]));
        }
    }
    __syncthreads();

    const int n0 = bin * 256 + quarter * 64;
    const int row = t >> 2, q = t & 3;
    int n = n0 + row;
    if (n < NN) {
        nf4 v;
        v.x = acc[row * 17 + q * 4 + 0];
        v.y = acc[row * 17 + q * 4 + 1];
        v.z = acc[row * 17 + q * 4 + 2];
        v.w = acc[row * 17 + q * 4 + 3];
        __builtin_nontemporal_store(v, (nf4*)&agg[((size_t)ro * NN + n) * DO + q * 4]);
    }
}

// ---------------------------------------------------------------------------
// Stage 5: out[n] += (1/11) * sum_ro proj(expmap0(agg[ro][n]))
__global__ __launch_bounds__(256) void k_final(const float* __restrict__ agg,
                                               float* __restrict__ out, int nrel) {
    int t = blockIdx.x * blockDim.x + threadIdx.x;
    int n = t >> 4, o = t & 15;
    if (n >= NN) return;
    float oa = 0.f;
    for (int ro = 0; ro < nrel; ++ro) {
        float u = __builtin_nontemporal_load(&agg[((size_t)ro * NN + n) * DO + o]);
        float ss = u * u;
        ss += __shfl_xor(ss, 1, 16);
        ss += __shfl_xor(ss, 2, 16);
        ss += __shfl_xor(ss, 4, 16);
        ss += __shfl_xor(ss, 8, 16);
        float un = fmaxf(sqrtf(ss), MIN_NORM);
        float th = tanhf(un);
        float rn = fmaxf(th, MIN_NORM);
        float sc = (rn > MAXNORM) ? (MAXNORM / rn) : 1.0f;
        oa += u * (th / un) * sc;
    }
    out[(size_t)n * DO + o] += oa * (1.0f / 11.0f);
}

__global__ void k_init_out(const float* __restrict__ bias, float* __restrict__ out) {
    int idx = blockIdx.x * blockDim.x + threadIdx.x;
    if (idx < NN * 16) out[idx] = bias[idx & 15];
}

// ---------------------------------------------------------------------------
extern "C" void kernel_launch(void* const* d_in, const int* in_sizes, int n_in,
                              void* d_out, int out_size, void* d_ws, size_t ws_size,
                              hipStream_t stream) {
    const float* x        = (const float*)d_in[0];
    const int*   adj_rows = (const int*)d_in[1];
    const int*   adj_cols = (const int*)d_in[2];
    const float* adj_vals = (const float*)d_in[3];
    const float* adj_w    = (const float*)d_in[4];
    const float* bias     = (const float*)d_in[5];
    float*       out      = (float*)d_out;

    char* p = (char*)d_ws;
    auto alloc = [&](size_t bytes) {
        char* r = p;
        p += (bytes + 255) & ~(size_t)255;
        return r;
    };
    float*  scale   = (float*)alloc((size_t)NN * 4);
    __half* support = (__half*)alloc((size_t)NADJ * NN * DO * 2);    // 35.2 MB fp16

    size_t used    = (size_t)(p - (char*)d_ws);
    size_t per_rel = ((size_t)NBINS * 4 + 256)
                   + ((size_t)NBINS * SEGCAP * 8 + 256)
                   + ((size_t)NN * DO * 4 + 256);                    // ~20.8 MB
    size_t avail   = (ws_size > used) ? ws_size - used : 0;
    int cr = (int)(avail / per_rel);
    if (cr < 1) cr = 1;
    if (cr > NADJ) cr = NADJ;
    int*    gcur   = (int*)alloc((size_t)cr * NBINS * 4);
    float2* packed = (float2*)alloc((size_t)cr * NBINS * SEGCAP * 8);
    float*  agg    = (float*)alloc((size_t)cr * NN * DO * 4);

    k_scale<<<512, 256, 0, stream>>>(x, scale);
    k_init_out<<<(NN * 16 + 255) / 256, 256, 0, stream>>>(bias, out);
    k_gemm<6><<<(NN + 63) / 64, 256, 0, stream>>>(x, scale, adj_w, support);
    k_gemm<5><<<(NN + 63) / 64, 256, 0, stream>>>(x, scale,
                                                  adj_w + (size_t)6 * DI * DO,
                                                  support + (size_t)6 * NN * DO);

    for (int r0 = 0; r0 < NADJ; r0 += cr) {
        int nr = (NADJ - r0 < cr) ? (NADJ - r0) : cr;
        hipMemsetAsync(gcur, 0, (size_t)nr * NBINS * 4, stream);
        k_bin<<<dim3(192, nr), 256, 0, stream>>>(adj_rows + (size_t)r0 * EE,
                                                 adj_cols + (size_t)r0 * EE,
                                                 adj_vals + (size_t)r0 * EE,
                                                 gcur, packed);
        for (int ro = 0; ro < nr; ++ro)
            k_agg<<<NBINS * 4, 256, 0, stream>>>(gcur, packed, support, agg, r0, ro);
        k_final<<<(NN * 16 + 255) / 256, 256, 0, stream>>>(agg, out, nr);
    }
}

// Round 10
// 2494.489 us; speedup vs baseline: 1.1280x; 1.1280x over previous
//
#include <hip/hip_runtime.h>
#include <hip/hip_fp16.h>
#include <math.h>

#define NN 100000       // nodes
#define NADJ 11         // relations
#define EE 1600000      // edges per relation
#define DI 128          // input dim
#define DO 16           // output dim

#define NBINS 391       // ceil(NN / 256): 256-row coarse bins
#define BCAP 8          // LDS staging per bin
#define SEGCAP 4608     // capacity per (rel,bin): mean 4096 + 8 sigma

static constexpr float MIN_NORM = 1e-15f;
static constexpr float MAXNORM  = 1.0f - 4e-3f;   // (1-PROJ_EPS)/sqrt(c), c=1

// clang vector types: __builtin_nontemporal_* rejects HIP_vector_type
typedef float nf2 __attribute__((ext_vector_type(2)));
typedef float nf4 __attribute__((ext_vector_type(4)));

// ---------------------------------------------------------------------------
// Stage 1: per-node tangent scale  s[n] = atanh(clip(||x_n||)) / max(||x_n||,1e-15)
__global__ void k_scale(const float* __restrict__ x, float* __restrict__ scale) {
    int lane   = threadIdx.x & 63;
    int wid    = (blockIdx.x * blockDim.x + threadIdx.x) >> 6;
    int nwav   = (gridDim.x * blockDim.x) >> 6;
    for (int n = wid; n < NN; n += nwav) {
        float2 v = ((const float2*)(x + (size_t)n * DI))[lane];
        float ss = v.x * v.x + v.y * v.y;
        #pragma unroll
        for (int off = 1; off < 64; off <<= 1) ss += __shfl_xor(ss, off);
        if (lane == 0) {
            float xn = fmaxf(sqrtf(ss), MIN_NORM);
            float xc = fminf(xn, 1.0f - 1e-7f);
            scale[n] = atanhf(xc) / xn;
        }
    }
}

// ---------------------------------------------------------------------------
// Stage 2: support[j][n][o] = scale[n] * (x[n,:] @ W[j][:,o])  -> fp16.
// Split launches (G=6,G=5): acc 24/20 regs.
// __launch_bounds__(256,2) ONLY — (256,3) and (256,4) both made the compiler
// cap VGPRs at/below the ~90 live values -> scratch spill (R3: 10 GB, R9:
// 1.7 GB HBM traffic). Never tighten the cap near the live-register count.
template<int G>
__global__ __launch_bounds__(256, 2) void k_gemm(const float* __restrict__ x,
                                                 const float* __restrict__ scale,
                                                 const float* __restrict__ W,
                                                 __half* __restrict__ support) {
    constexpr int COLS = 16 * G;
    __shared__ float xs[64][36];
    __shared__ float ws[COLS][36];
    const int t  = threadIdx.x;
    const int tc = t & 15;
    const int tr = t >> 4;
    const int n0 = blockIdx.x * 64;

    float acc[4][G];
    #pragma unroll
    for (int m = 0; m < 4; ++m)
        #pragma unroll
        for (int j = 0; j < G; ++j) acc[m][j] = 0.f;

    for (int kb = 0; kb < 4; ++kb) {
        __syncthreads();
        for (int idx = t; idx < 64 * 8; idx += 256) {
            int r = idx >> 3, k4 = idx & 7;
            int n = n0 + r;
            float4 v = make_float4(0.f, 0.f, 0.f, 0.f);
            if (n < NN) v = ((const float4*)(x + (size_t)n * DI + kb * 32))[k4];
            *(float4*)&xs[r][k4 * 4] = v;
        }
        for (int idx = t; idx < G * 32 * 4; idx += 256) {
            int j = idx >> 7, rem = idx & 127, kk = rem >> 2, o4 = rem & 3;
            float4 v = *(const float4*)(W + ((size_t)j * DI + kb * 32 + kk) * DO + o4 * 4);
            ws[j * 16 + o4 * 4 + 0][kk] = v.x;
            ws[j * 16 + o4 * 4 + 1][kk] = v.y;
            ws[j * 16 + o4 * 4 + 2][kk] = v.z;
            ws[j * 16 + o4 * 4 + 3][kk] = v.w;
        }
        __syncthreads();
        #pragma unroll
        for (int kk4 = 0; kk4 < 8; ++kk4) {
            float4 xv[4];
            #pragma unroll
            for (int m = 0; m < 4; ++m) xv[m] = *(const float4*)&xs[tr * 4 + m][kk4 * 4];
            #pragma unroll
            for (int j = 0; j < G; ++j) {
                float4 wv = *(const float4*)&ws[j * 16 + tc][kk4 * 4];
                #pragma unroll
                for (int m = 0; m < 4; ++m)
                    acc[m][j] += xv[m].x * wv.x + xv[m].y * wv.y
                               + xv[m].z * wv.z + xv[m].w * wv.w;
            }
        }
    }
    float sv[4];
    #pragma unroll
    for (int m = 0; m < 4; ++m) {
        int n = n0 + tr * 4 + m;
        sv[m] = (n < NN) ? scale[n] : 0.f;
    }
    float* st = &xs[0][0];          // reuse as [64][17]
    const int row = t >> 2, q = t & 3;
    for (int j = 0; j < G; ++j) {
        __syncthreads();
        #pragma unroll
        for (int m = 0; m < 4; ++m)
            st[(tr * 4 + m) * 17 + tc] = acc[m][j] * sv[m];
        __syncthreads();
        int n = n0 + row;
        if (n < NN) {
            __half2 h0 = __floats2half2_rn(st[row * 17 + q * 4 + 0],
                                           st[row * 17 + q * 4 + 1]);
            __half2 h1 = __floats2half2_rn(st[row * 17 + q * 4 + 2],
                                           st[row * 17 + q * 4 + 3]);
            uint2 u;
            u.x = *(unsigned*)&h0;
            u.y = *(unsigned*)&h1;
            *(uint2*)&support[((size_t)j * NN + n) * DO + q * 4] = u;  // 8 B/lane
        }
    }
}

// ---------------------------------------------------------------------------
// Stage 3: bin edges into 256-row coarse bins (LDS staging, cooperative flush).
__global__ __launch_bounds__(256) void k_bin(const int* __restrict__ rows,
                                             const int* __restrict__ cols,
                                             const float* __restrict__ vals,
                                             int* __restrict__ gcur,
                                             float2* __restrict__ packed) {
    __shared__ int    cnt[NBINS];
    __shared__ float2 buf[NBINS][BCAP];
    __shared__ int    fl_b[256];
    __shared__ int    fl_gp[256];
    __shared__ int    nflush;

    const int t  = threadIdx.x;
    const int ro = blockIdx.y;
    const size_t ebase = (size_t)ro * EE;
    int*    cur = gcur + (size_t)ro * NBINS;
    float2* pk  = packed + (size_t)ro * NBINS * SEGCAP;

    const int nper = (EE + gridDim.x - 1) / gridDim.x;
    const int e0 = blockIdx.x * nper;
    const int e1 = (e0 + nper < EE) ? e0 + nper : EE;

    for (int b = t; b < NBINS; b += 256) cnt[b] = 0;
    __syncthreads();

    for (int eb = e0; eb < e1; eb += 256) {
        int e = eb + t;
        if (e < e1) {
            int   r = __builtin_nontemporal_load(&rows[ebase + e]);
            int   c = __builtin_nontemporal_load(&cols[ebase + e]);
            float v = __builtin_nontemporal_load(&vals[ebase + e]);
            int bin = r >> 8;
            float ptag = __uint_as_float(((unsigned)(r & 255) << 17) | (unsigned)c);
            int pos = atomicAdd(&cnt[bin], 1);
            if (pos < BCAP) {
                buf[bin][pos] = make_float2(v, ptag);
            } else {
                int gp = atomicAdd(&cur[bin], 1);
                if (gp < SEGCAP) pk[(size_t)bin * SEGCAP + gp] = make_float2(v, ptag);
            }
        }
        __syncthreads();
        if (t == 0) nflush = 0;
        __syncthreads();
        for (int b = t; b < NBINS; b += 256) {
            int c = cnt[b];
            if (c >= BCAP) {
                int i = atomicAdd(&nflush, 1);
                fl_b[i]  = b;
                fl_gp[i] = atomicAdd(&cur[b], BCAP);
                cnt[b] = 0;
            }
        }
        __syncthreads();
        int nf = nflush, o = t & 7;
        for (int j = t >> 3; j < nf; j += 32) {
            int b = fl_b[j];
            int gp = fl_gp[j] + o;
            if (gp < SEGCAP) pk[(size_t)b * SEGCAP + gp] = buf[b][o];
        }
        __syncthreads();
    }
    int o = t & 7;
    for (int b = t >> 3; b < NBINS; b += 32) {
        int c = cnt[b];
        int gp0 = 0;
        if (o == 0 && c > 0) gp0 = atomicAdd(&cur[b], c);
        gp0 = __shfl(gp0, (threadIdx.x & 63) & ~7);
        if (o < c) {
            int gp = gp0 + o;
            if (gp < SEGCAP) pk[(size_t)b * SEGCAP + gp] = buf[b][o];
        }
    }
}

// ---------------------------------------------------------------------------
// Stage 4: ONE LAUNCH PER RELATION (stream serialization => only this rel's
// 3.2 MB fp16 support slice is gathered during the launch -> L2-resident on
// every XCD). Quarter-split bins: block bx -> (bin = bx>>2, quarter = bx&3),
// 64-row LDS acc. 8-edge batches, 8 gathers in flight.
__global__ __launch_bounds__(256) void k_agg(const int* __restrict__ gcur,
                                             const float2* __restrict__ packed,
                                             const __half* __restrict__ support,
                                             float* __restrict__ agg,
                                             int r0, int ro) {
    __shared__ float acc[64 * 17];
    const int bx      = blockIdx.x;
    const int bin     = bx >> 2;
    const int quarter = bx & 3;
    const int t = threadIdx.x;
    const int o = t & 15;
    const int g = t >> 4;

    for (int i = t; i < 64 * 17; i += 256) acc[i] = 0.f;
    __syncthreads();

    int c = gcur[(size_t)ro * NBINS + bin];
    if (c > SEGCAP) c = SEGCAP;
    const float2* seg = packed + ((size_t)ro * NBINS + bin) * SEGCAP;
    const __half* sup = support + (size_t)(r0 + ro) * NN * DO;

    const int nb = c >> 3;
    for (int b = g; b < nb; b += 16) {
        const float4* s4 = (const float4*)&seg[b * 8];
        float4 s0 = s4[0], s1 = s4[1], s2 = s4[2], s3 = s4[3];
        float    v[8];
        unsigned p[8];
        v[0] = s0.x; p[0] = __float_as_uint(s0.y);
        v[1] = s0.z; p[1] = __float_as_uint(s0.w);
        v[2] = s1.x; p[2] = __float_as_uint(s1.y);
        v[3] = s1.z; p[3] = __float_as_uint(s1.w);
        v[4] = s2.x; p[4] = __float_as_uint(s2.y);
        v[5] = s2.z; p[5] = __float_as_uint(s2.w);
        v[6] = s3.x; p[6] = __float_as_uint(s3.y);
        v[7] = s3.z; p[7] = __float_as_uint(s3.w);
        float sv[8];
        bool  keep[8];
        #pragma unroll
        for (int k = 0; k < 8; ++k) {
            keep[k] = (int)((p[k] >> 23) & 3u) == quarter;   // row bits 6..7
            sv[k] = keep[k] ? __half2float(sup[(size_t)(p[k] & 0x1FFFFu) * DO + o]) : 0.f;
        }
        #pragma unroll
        for (int k = 0; k < 8; ++k)
            if (keep[k])
                atomicAdd(&acc[((p[k] >> 17) & 63u) * 17 + o], v[k] * sv[k]);
    }
    if (g == 0) {
        for (int i = nb * 8; i < c; ++i) {
            float2 e = seg[i];
            unsigned p = __float_as_uint(e.y);
            if ((int)((p >> 23) & 3u) == quarter)
                atomicAdd(&acc[((p >> 17) & 63u) * 17 + o],
                          e.x * __half2float(sup[(size_t)(p & 0x1FFFFu) * DO + o]));
        }
    }
    __syncthreads();

    const int n0 = bin * 256 + quarter * 64;
    const int row = t >> 2, q = t & 3;
    int n = n0 + row;
    if (n < NN) {
        nf4 v;
        v.x = acc[row * 17 + q * 4 + 0];
        v.y = acc[row * 17 + q * 4 + 1];
        v.z = acc[row * 17 + q * 4 + 2];
        v.w = acc[row * 17 + q * 4 + 3];
        __builtin_nontemporal_store(v, (nf4*)&agg[((size_t)ro * NN + n) * DO + q * 4]);
    }
}

// ---------------------------------------------------------------------------
// Stage 5: out[n] += (1/11) * sum_ro proj(expmap0(agg[ro][n]))
__global__ __launch_bounds__(256) void k_final(const float* __restrict__ agg,
                                               float* __restrict__ out, int nrel) {
    int t = blockIdx.x * blockDim.x + threadIdx.x;
    int n = t >> 4, o = t & 15;
    if (n >= NN) return;
    float oa = 0.f;
    for (int ro = 0; ro < nrel; ++ro) {
        float u = __builtin_nontemporal_load(&agg[((size_t)ro * NN + n) * DO + o]);
        float ss = u * u;
        ss += __shfl_xor(ss, 1, 16);
        ss += __shfl_xor(ss, 2, 16);
        ss += __shfl_xor(ss, 4, 16);
        ss += __shfl_xor(ss, 8, 16);
        float un = fmaxf(sqrtf(ss), MIN_NORM);
        float th = tanhf(un);
        float rn = fmaxf(th, MIN_NORM);
        float sc = (rn > MAXNORM) ? (MAXNORM / rn) : 1.0f;
        oa += u * (th / un) * sc;
    }
    out[(size_t)n * DO + o] += oa * (1.0f / 11.0f);
}

__global__ void k_init_out(const float* __restrict__ bias, float* __restrict__ out) {
    int idx = blockIdx.x * blockDim.x + threadIdx.x;
    if (idx < NN * 16) out[idx] = bias[idx & 15];
}

// ---------------------------------------------------------------------------
extern "C" void kernel_launch(void* const* d_in, const int* in_sizes, int n_in,
                              void* d_out, int out_size, void* d_ws, size_t ws_size,
                              hipStream_t stream) {
    const float* x        = (const float*)d_in[0];
    const int*   adj_rows = (const int*)d_in[1];
    const int*   adj_cols = (const int*)d_in[2];
    const float* adj_vals = (const float*)d_in[3];
    const float* adj_w    = (const float*)d_in[4];
    const float* bias     = (const float*)d_in[5];
    float*       out      = (float*)d_out;

    char* p = (char*)d_ws;
    auto alloc = [&](size_t bytes) {
        char* r = p;
        p += (bytes + 255) & ~(size_t)255;
        return r;
    };
    float*  scale   = (float*)alloc((size_t)NN * 4);
    __half* support = (__half*)alloc((size_t)NADJ * NN * DO * 2);    // 35.2 MB fp16

    size_t used    = (size_t)(p - (char*)d_ws);
    size_t per_rel = ((size_t)NBINS * 4 + 256)
                   + ((size_t)NBINS * SEGCAP * 8 + 256)
                   + ((size_t)NN * DO * 4 + 256);                    // ~20.8 MB
    size_t avail   = (ws_size > used) ? ws_size - used : 0;
    int cr = (int)(avail / per_rel);
    if (cr < 1) cr = 1;
    if (cr > NADJ) cr = NADJ;
    int*    gcur   = (int*)alloc((size_t)cr * NBINS * 4);
    float2* packed = (float2*)alloc((size_t)cr * NBINS * SEGCAP * 8);
    float*  agg    = (float*)alloc((size_t)cr * NN * DO * 4);

    k_scale<<<512, 256, 0, stream>>>(x, scale);
    k_init_out<<<(NN * 16 + 255) / 256, 256, 0, stream>>>(bias, out);
    k_gemm<6><<<(NN + 63) / 64, 256, 0, stream>>>(x, scale, adj_w, support);
    k_gemm<5><<<(NN + 63) / 64, 256, 0, stream>>>(x, scale,
                                                  adj_w + (size_t)6 * DI * DO,
                                                  support + (size_t)6 * NN * DO);

    for (int r0 = 0; r0 < NADJ; r0 += cr) {
        int nr = (NADJ - r0 < cr) ? (NADJ - r0) : cr;
        hipMemsetAsync(gcur, 0, (size_t)nr * NBINS * 4, stream);
        k_bin<<<dim3(192, nr), 256, 0, stream>>>(adj_rows + (size_t)r0 * EE,
                                                 adj_cols + (size_t)r0 * EE,
                                                 adj_vals + (size_t)r0 * EE,
                                                 gcur, packed);
        for (int ro = 0; ro < nr; ++ro)
            k_agg<<<NBINS * 4, 256, 0, stream>>>(gcur, packed, support, agg, r0, ro);
        k_final<<<(NN * 16 + 255) / 256, 256, 0, stream>>>(agg, out, nr);
    }
}